// Round 4
// baseline (153.906 us; speedup 1.0000x reference)
//
#include <hip/hip_runtime.h>

// B=32, T=2048, D=64, K=4, KD=256
// out[b,t,j] = m*ha + (1-m)*(g*h_fwd + (1-g)*ha)
//   d = j % 64, m = M[b,t,d], delta = deltas[b,t,d] in {1,2,3,4} (clamped <= t+1)
//   g = exp(-relu(delta*W[j] + b[j]))
//   h_fwd = h_a[b, t-(int(delta)-1), j]  -> one of rows t, t-1, t-2, t-3
//
// v5: v1 shape + XCD-aware block swizzle (single-variable experiment).
//   Default dispatch round-robins consecutive blocks across the 8 XCDs, so
//   the 4 readers of each h_a row (ha@t, c1@t+1, c2@t+2, c3@t+3) sit on 4
//   DIFFERENT XCDs -> each h_a line is filled into ~4 private L2s (~256 MB
//   of L3->L2 fill for a 64 MB array). Chunking blocks per-XCD makes the
//   candidate rows same-CU (L1) or same-XCD (local L2) hits, collapsing the
//   amplification to ~1x. Bijection: grid=16384, swz=(bid&7)*2048+(bid>>3).

#define TD_T 2048
#define TD_KD 256
#define TD_D 64

typedef float f32x4 __attribute__((ext_vector_type(4)));

__global__ __launch_bounds__(256) void TemporalDecay_89524298318172_kernel(
    const float* __restrict__ h_a,
    const float* __restrict__ deltas,
    const float* __restrict__ M,
    const float* __restrict__ W,
    const float* __restrict__ bias,
    float* __restrict__ out)
{
    // XCD-aware chunked swizzle: XCD x gets original-contiguous blocks
    // [x*2048, (x+1)*2048) -> contiguous rows on one XCD's L2.
    const int bid = blockIdx.x;
    const int swz = (bid & 7) * (gridDim.x >> 3) + (bid >> 3);

    const int gid = swz * blockDim.x + threadIdx.x;
    const int q   = gid & 63;        // which float4 within the 256-wide row
    const int row = gid >> 6;        // b*T + t
    const int t   = row & (TD_T - 1);
    const int j0  = q << 2;          // 0..252, multiple of 4
    const int d0  = j0 & (TD_D - 1); // no wrap inside a float4 (4 | 64)

    const size_t row_off = (size_t)row * TD_KD + j0;

    // All loads issue with no inter-load dependencies.
    const f32x4 ha4 = *(const f32x4*)(h_a    + row_off);
    const f32x4 m4  = *(const f32x4*)(M      + (size_t)row * TD_D + d0);
    const f32x4 dl4 = *(const f32x4*)(deltas + (size_t)row * TD_D + d0);
    const f32x4 w4  = *(const f32x4*)(W    + j0);
    const f32x4 b4  = *(const f32x4*)(bias + j0);

    // Candidate rows t-1, t-2, t-3 (clamped; unselected when t-r < 0 since
    // delta <= t+1 guarantees the selected row index is >= 0).
    const int r1 = (t >= 1) ? t - 1 : 0;
    const int r2 = (t >= 2) ? t - 2 : 0;
    const int r3 = (t >= 3) ? t - 3 : 0;
    const size_t bt_base = (size_t)(row - t) * TD_KD + j0;  // b*T*KD + j0
    const f32x4 c1 = *(const f32x4*)(h_a + bt_base + (size_t)r1 * TD_KD);
    const f32x4 c2 = *(const f32x4*)(h_a + bt_base + (size_t)r2 * TD_KD);
    const f32x4 c3 = *(const f32x4*)(h_a + bt_base + (size_t)r3 * TD_KD);

    f32x4 res;
#pragma unroll
    for (int e = 0; e < 4; ++e) {
        const float delta = dl4[e];
        const float g = __expf(-fmaxf(fmaf(delta, w4[e], b4[e]), 0.0f));
        const int di = (int)delta;  // 1..4
        float hf = ha4[e];
        hf = (di == 2) ? c1[e] : hf;
        hf = (di == 3) ? c2[e] : hf;
        hf = (di == 4) ? c3[e] : hf;
        const float m = m4[e];
        res[e] = m * ha4[e] + (1.0f - m) * (g * hf + (1.0f - g) * ha4[e]);
    }

    __builtin_nontemporal_store(res, (f32x4*)(out + row_off));
}

extern "C" void kernel_launch(void* const* d_in, const int* in_sizes, int n_in,
                              void* d_out, int out_size, void* d_ws, size_t ws_size,
                              hipStream_t stream) {
    const float* h_a    = (const float*)d_in[0];
    const float* deltas = (const float*)d_in[1];
    const float* M      = (const float*)d_in[2];
    const float* W      = (const float*)d_in[3];
    const float* bias   = (const float*)d_in[4];
    float* out          = (float*)d_out;

    // total float4 threads = B*T*KD/4 = 4,194,304
    const int total = in_sizes[0] / 4;
    const int block = 256;
    const int grid = (total + block - 1) / block;  // 16384 (multiple of 8)
    TemporalDecay_89524298318172_kernel<<<grid, block, 0, stream>>>(
        h_a, deltas, M, W, bias, out);
}

// Round 5
// 147.196 us; speedup vs baseline: 1.0456x; 1.0456x over previous
//
#include <hip/hip_runtime.h>

// B=32, T=2048, D=64, K=4, KD=256
// out[b,t,j] = m*ha + (1-m)*(g*h_fwd + (1-g)*ha)
//   d = j % 64, m = M[b,t,d], delta = deltas[b,t,d] in {1,2,3,4} (clamped <= t+1)
//   g = exp(-relu(delta*W[j] + b[j]))
//   h_fwd = h_a[b, t-(int(delta)-1), j]  -> one of rows t, t-1, t-2, t-3
//
// v6: depth-4 burst, phase-separated read/compute/write (no loop, no
// loop-carried deps). Rationale: all byte/instr/occupancy/store-policy/
// locality levers are individually falsified; waves sit ~8600 cycles in a
// saturated memory queue draining at 3.3 TB/s while copy/fill hit 6.3.
// Remaining structural difference vs those references: fine-grained
// read<->write interleave (10 loads then 1 store per wave). This kernel
// issues a pure 15-load burst, computes, then a pure 4-store burst --
// 4x same-direction run-length -- while keeping v1's concurrency shape
// (4096 blocks = 16/CU, every load independent).
//   t0 = multiple of 4 => candidate clamp is all-or-nothing (t0==0 only),
//   and rows t0+1..t0+3 gather from the burst's own ha registers.

#define TD_T 2048
#define TD_KD 256
#define TD_D 64

typedef float f32x4 __attribute__((ext_vector_type(4)));

__device__ __forceinline__ f32x4 td_row(const f32x4 ha, const f32x4 m4, const f32x4 dl4,
                                        const f32x4 c1, const f32x4 c2, const f32x4 c3,
                                        const f32x4 w4, const f32x4 b4)
{
    f32x4 res;
#pragma unroll
    for (int e = 0; e < 4; ++e) {
        const float delta = dl4[e];
        const float g = __expf(-fmaxf(fmaf(delta, w4[e], b4[e]), 0.0f));
        // delta is an exact small integer in float; compares are exact
        float hf = ha[e];
        hf = (delta > 1.5f) ? c1[e] : hf;
        hf = (delta > 2.5f) ? c2[e] : hf;
        hf = (delta > 3.5f) ? c3[e] : hf;
        const float m = m4[e];
        res[e] = m * ha[e] + (1.0f - m) * (g * hf + (1.0f - g) * ha[e]);
    }
    return res;
}

__global__ __launch_bounds__(256) void TemporalDecay_89524298318172_kernel(
    const float* __restrict__ h_a,
    const float* __restrict__ deltas,
    const float* __restrict__ M,
    const float* __restrict__ W,
    const float* __restrict__ bias,
    float* __restrict__ out)
{
    const int gid  = blockIdx.x * blockDim.x + threadIdx.x;
    const int q    = gid & 63;           // float4 column within the 256-wide row
    const int seg  = gid >> 6;           // 4-row segment index
    const int row0 = seg << 2;
    const int t0   = row0 & (TD_T - 1);  // multiple of 4
    const int j0   = q << 2;             // 0..252
    const int d0   = j0 & (TD_D - 1);    // no wrap inside a float4 (4 | 64)

    const float* __restrict__ hp = h_a    + (size_t)row0 * TD_KD + j0;
    const float* __restrict__ mp = M      + (size_t)row0 * TD_D  + d0;
    const float* __restrict__ dp = deltas + (size_t)row0 * TD_D  + d0;
    float* __restrict__ op       = out    + (size_t)row0 * TD_KD + j0;

    // ---- pure read burst: 17 independent loads ----
    const f32x4 w4 = *(const f32x4*)(W    + j0);
    const f32x4 b4 = *(const f32x4*)(bias + j0);

    // Candidates for row t0. t0 % 4 == 0, so either t0 == 0 (clamp all three
    // to row t0; never selected since delta <= t+1) or t0 >= 4 (all valid).
    const int cstep = (t0 == 0) ? 0 : TD_KD;
    const f32x4 c1 = *(const f32x4*)(hp - 1 * cstep);
    const f32x4 c2 = *(const f32x4*)(hp - 2 * cstep);
    const f32x4 c3 = *(const f32x4*)(hp - 3 * cstep);

    const f32x4 ha0 = *(const f32x4*)(hp);
    const f32x4 ha1 = *(const f32x4*)(hp + TD_KD);
    const f32x4 ha2 = *(const f32x4*)(hp + 2 * TD_KD);
    const f32x4 ha3 = *(const f32x4*)(hp + 3 * TD_KD);

    const f32x4 m0 = *(const f32x4*)(mp);
    const f32x4 m1 = *(const f32x4*)(mp + TD_D);
    const f32x4 m2 = *(const f32x4*)(mp + 2 * TD_D);
    const f32x4 m3 = *(const f32x4*)(mp + 3 * TD_D);

    const f32x4 dl0 = *(const f32x4*)(dp);
    const f32x4 dl1 = *(const f32x4*)(dp + TD_D);
    const f32x4 dl2 = *(const f32x4*)(dp + 2 * TD_D);
    const f32x4 dl3 = *(const f32x4*)(dp + 3 * TD_D);

    // ---- compute phase (candidates roll through the burst's registers) ----
    const f32x4 r0 = td_row(ha0, m0, dl0, c1,  c2,  c3, w4, b4);
    const f32x4 r1 = td_row(ha1, m1, dl1, ha0, c1,  c2, w4, b4);
    const f32x4 r2 = td_row(ha2, m2, dl2, ha1, ha0, c1, w4, b4);
    const f32x4 r3 = td_row(ha3, m3, dl3, ha2, ha1, ha0, w4, b4);

    // ---- pure write burst ----
    __builtin_nontemporal_store(r0, (f32x4*)(op));
    __builtin_nontemporal_store(r1, (f32x4*)(op + TD_KD));
    __builtin_nontemporal_store(r2, (f32x4*)(op + 2 * TD_KD));
    __builtin_nontemporal_store(r3, (f32x4*)(op + 3 * TD_KD));
}

extern "C" void kernel_launch(void* const* d_in, const int* in_sizes, int n_in,
                              void* d_out, int out_size, void* d_ws, size_t ws_size,
                              hipStream_t stream) {
    const float* h_a    = (const float*)d_in[0];
    const float* deltas = (const float*)d_in[1];
    const float* M      = (const float*)d_in[2];
    const float* W      = (const float*)d_in[3];
    const float* bias   = (const float*)d_in[4];
    float* out          = (float*)d_out;

    // rows = B*T = 65536; 4 rows per 64-lane wave-column
    const int rows = in_sizes[0] / TD_KD;
    const int total_threads = (rows / 4) * 64;     // 1,048,576
    const int block = 256;
    const int grid = total_threads / block;        // 4096 (16 blocks/CU)
    TemporalDecay_89524298318172_kernel<<<grid, block, 0, stream>>>(
        h_a, deltas, M, W, bias, out);
}